// Round 2
// baseline (285.074 us; speedup 1.0000x reference)
//
#include <hip/hip_runtime.h>

#define D_IN   128
#define NHEAD  4
#define D_OUT  128
#define HDIM   512   // NHEAD * D_OUT
#define NEG    0.2f

// ---------------------------------------------------------------------------
// Kernel 1: h = x @ W   (M x 128) * (128 x 512), fp32 vector GEMM
// 64x64 tile, K in two 64-chunks staged in LDS (34.8 KB), 4x4 outputs/thread.
// A staged K-major (AsT[k][row]) so compute-side b128 reads are conflict-free.
// ---------------------------------------------------------------------------
__global__ __launch_bounds__(256) void gemm_h(const float* __restrict__ x,
                                              const float* __restrict__ W,
                                              float* __restrict__ h, int M) {
    __shared__ float AsT[64][68];   // [k][row], pad 64->68
    __shared__ float Bs[64][68];    // [k][col], pad 64->68
    const int tid  = threadIdx.x;
    const int row0 = blockIdx.x * 64;
    const int col0 = blockIdx.y * 64;
    const int tx = tid & 15, ty = tid >> 4;

    float c[4][4] = {};

    for (int kb = 0; kb < 128; kb += 64) {
        // stage A: 64 rows x 64 k = 1024 float4, 4/thread, coalesced read,
        // transposed scatter into AsT
#pragma unroll
        for (int it = 0; it < 4; ++it) {
            int flat = tid + it * 256;          // 0..1023
            int r  = flat >> 4;                 // row within tile
            int kf = flat & 15;                 // float4 index within k-chunk
            int grow = row0 + r; if (grow >= M) grow = M - 1;
            float4 v = *(const float4*)(x + (size_t)grow * D_IN + kb + kf * 4);
            AsT[kf * 4 + 0][r] = v.x;
            AsT[kf * 4 + 1][r] = v.y;
            AsT[kf * 4 + 2][r] = v.z;
            AsT[kf * 4 + 3][r] = v.w;
        }
        // stage B: 64 k-rows x 64 cols = 1024 float4, 4/thread, coalesced
#pragma unroll
        for (int it = 0; it < 4; ++it) {
            int flat = tid + it * 256;
            int r  = flat >> 4;                 // k within chunk
            int cf = flat & 15;
            float4 v = *(const float4*)(W + (size_t)(kb + r) * HDIM + col0 + cf * 4);
            *(float4*)(&Bs[r][cf * 4]) = v;
        }
        __syncthreads();

#pragma unroll 4
        for (int kk = 0; kk < 64; ++kk) {
            float4 a = *(const float4*)(&AsT[kk][ty * 4]);
            float4 b = *(const float4*)(&Bs[kk][tx * 4]);
            const float* af = reinterpret_cast<const float*>(&a);
            const float* bf = reinterpret_cast<const float*>(&b);
#pragma unroll
            for (int i = 0; i < 4; ++i)
#pragma unroll
                for (int j = 0; j < 4; ++j)
                    c[i][j] += af[i] * bf[j];
        }
        __syncthreads();
    }

#pragma unroll
    for (int i = 0; i < 4; ++i) {
        int grow = row0 + ty * 4 + i;
        if (grow < M) {
            float4 v = make_float4(c[i][0], c[i][1], c[i][2], c[i][3]);
            *(float4*)(h + (size_t)grow * HDIM + col0 + tx * 4) = v;
        }
    }
}

// ---------------------------------------------------------------------------
// Kernel 2: a_src[n,h] = dot(h[n,h,:], att_src[h,:]); same for att_dst
// one block per node, wave w handles head w
// ---------------------------------------------------------------------------
__global__ __launch_bounds__(256) void compute_a(const float* __restrict__ h,
                                                 const float* __restrict__ att_src,
                                                 const float* __restrict__ att_dst,
                                                 float* __restrict__ a_src,
                                                 float* __restrict__ a_dst, int Nn) {
    int n = blockIdx.x;
    int wave = threadIdx.x >> 6;
    int lane = threadIdx.x & 63;
    const float* hr = h + (size_t)n * HDIM + wave * D_OUT;
    float v1 = hr[lane], v2 = hr[64 + lane];
    float s = v1 * att_src[wave * D_OUT + lane] + v2 * att_src[wave * D_OUT + 64 + lane];
    float d = v1 * att_dst[wave * D_OUT + lane] + v2 * att_dst[wave * D_OUT + 64 + lane];
#pragma unroll
    for (int off = 32; off > 0; off >>= 1) {
        s += __shfl_down(s, off);
        d += __shfl_down(d, off);
    }
    if (lane == 0) {
        a_src[n * NHEAD + wave] = s;
        a_dst[n * NHEAD + wave] = d;
    }
}

// ---------------------------------------------------------------------------
// CSR build: count -> scan -> fill (self-loops appended as virtual edges)
// edge_index arrives as int32 (harness converts integer inputs to int32).
// ---------------------------------------------------------------------------
__global__ void count_deg(const int* __restrict__ ei, int E, int Nn,
                          int* __restrict__ deg) {
    int i = blockIdx.x * blockDim.x + threadIdx.x;
    if (i >= E + Nn) return;
    int dst = (i < E) ? ei[E + i] : (i - E);
    atomicAdd(&deg[dst], 1);
}

__global__ __launch_bounds__(1024) void scan_offsets(const int* __restrict__ deg,
                                                     int* __restrict__ offs, int n) {
    __shared__ int buf[1024];
    __shared__ int carry;
    if (threadIdx.x == 0) carry = 0;
    __syncthreads();
    for (int base = 0; base < n; base += 1024) {
        int i = base + (int)threadIdx.x;
        int v = (i < n) ? deg[i] : 0;
        buf[threadIdx.x] = v;
        __syncthreads();
        for (int off = 1; off < 1024; off <<= 1) {
            int t = (threadIdx.x >= (unsigned)off) ? buf[threadIdx.x - off] : 0;
            __syncthreads();
            buf[threadIdx.x] += t;
            __syncthreads();
        }
        if (i < n) offs[i + 1] = carry + buf[threadIdx.x];
        __syncthreads();
        if (threadIdx.x == 1023) carry += buf[1023];
        __syncthreads();
    }
    if (threadIdx.x == 0) offs[0] = 0;
}

__global__ void fill_csr(const int* __restrict__ ei, int E, int Nn,
                         const int* __restrict__ offs, int* __restrict__ fill,
                         int* __restrict__ csr) {
    int i = blockIdx.x * blockDim.x + threadIdx.x;
    if (i >= E + Nn) return;
    int src, dst;
    if (i < E) { src = ei[i]; dst = ei[E + i]; }
    else       { src = dst = i - E; }
    int pos = offs[dst] + atomicAdd(&fill[dst], 1);
    csr[pos] = src;
}

// ---------------------------------------------------------------------------
// Kernel 6: per-dst softmax + weighted aggregation + head-mean + bias + relu
// one block (256 thr) per node; thread t owns flat dims t and t+256 of [4x128]
// ---------------------------------------------------------------------------
__global__ __launch_bounds__(256) void aggregate(const float* __restrict__ h,
                                                 const float* __restrict__ a_src,
                                                 const float* __restrict__ a_dst,
                                                 const int* __restrict__ offs,
                                                 const int* __restrict__ csr,
                                                 const float* __restrict__ bias,
                                                 float* __restrict__ out, int Nn) {
    int n = blockIdx.x;
    int tid = threadIdx.x;
    int beg = offs[n], end = offs[n + 1];
    int h0 = tid >> 7;         // head 0 or 1
    int h1 = h0 + 2;           // head 2 or 3
    float ad0 = a_dst[n * NHEAD + h0];
    float ad1 = a_dst[n * NHEAD + h1];

    // pass 1: per-head max of leaky(logit)
    float m0 = -1e30f, m1 = -1e30f;
    for (int e = beg; e < end; ++e) {
        int s = csr[e];
        float l0 = a_src[s * NHEAD + h0] + ad0; l0 = (l0 >= 0.f) ? l0 : NEG * l0;
        float l1 = a_src[s * NHEAD + h1] + ad1; l1 = (l1 >= 0.f) ? l1 : NEG * l1;
        m0 = fmaxf(m0, l0); m1 = fmaxf(m1, l1);
    }
    // pass 2: denom + weighted feature accumulation
    float acc0 = 0.f, acc1 = 0.f, den0 = 0.f, den1 = 0.f;
    for (int e = beg; e < end; ++e) {
        int s = csr[e];
        float l0 = a_src[s * NHEAD + h0] + ad0; l0 = (l0 >= 0.f) ? l0 : NEG * l0;
        float l1 = a_src[s * NHEAD + h1] + ad1; l1 = (l1 >= 0.f) ? l1 : NEG * l1;
        float e0 = __expf(l0 - m0), e1 = __expf(l1 - m1);
        den0 += e0; den1 += e1;
        const float* hs = h + (size_t)s * HDIM;
        acc0 += e0 * hs[tid];          // flat dim tid       -> (h0, d)
        acc1 += e1 * hs[tid + 256];    // flat dim tid+256   -> (h1, d)
    }

    __shared__ float red[512];
    red[tid]       = acc0 / den0;
    red[tid + 256] = acc1 / den1;
    __syncthreads();
    if (tid < 128) {
        float v = red[tid] + red[tid + 128] + red[tid + 256] + red[tid + 384];
        v = v * 0.25f + bias[tid];
        out[(size_t)n * D_OUT + tid] = fmaxf(v, 0.f);
    }
}

// ---------------------------------------------------------------------------
extern "C" void kernel_launch(void* const* d_in, const int* in_sizes, int n_in,
                              void* d_out, int out_size, void* d_ws, size_t ws_size,
                              hipStream_t stream) {
    const float* x       = (const float*)d_in[0];
    const float* W       = (const float*)d_in[1];
    const float* att_src = (const float*)d_in[2];
    const float* att_dst = (const float*)d_in[3];
    const float* bias    = (const float*)d_in[4];
    const int*   ei      = (const int*)d_in[5];   // int inputs arrive as int32
    float*       out     = (float*)d_out;

    const int N    = in_sizes[0] / D_IN;
    const int E    = in_sizes[5] / 2;
    const int Etot = E + N;

    char* ws = (char*)d_ws;
    size_t off = 0;
    auto alloc = [&](size_t bytes) -> char* {
        char* p = ws + off;
        off += (bytes + 255) & ~(size_t)255;
        return p;
    };
    float* h     = (float*)alloc((size_t)N * HDIM * sizeof(float));
    float* a_src = (float*)alloc((size_t)N * NHEAD * sizeof(float));
    float* a_dst = (float*)alloc((size_t)N * NHEAD * sizeof(float));
    int*   deg   = (int*)alloc((size_t)N * sizeof(int));
    int*   offs  = (int*)alloc((size_t)(N + 1) * sizeof(int));
    int*   fillc = (int*)alloc((size_t)N * sizeof(int));
    int*   csr   = (int*)alloc((size_t)Etot * sizeof(int));

    hipMemsetAsync(deg,   0, (size_t)N * sizeof(int), stream);
    hipMemsetAsync(fillc, 0, (size_t)N * sizeof(int), stream);

    dim3 ggrid((N + 63) / 64, HDIM / 64);
    gemm_h<<<ggrid, 256, 0, stream>>>(x, W, h, N);
    compute_a<<<N, 256, 0, stream>>>(h, att_src, att_dst, a_src, a_dst, N);
    count_deg<<<(Etot + 255) / 256, 256, 0, stream>>>(ei, E, N, deg);
    scan_offsets<<<1, 1024, 0, stream>>>(deg, offs, N);
    fill_csr<<<(Etot + 255) / 256, 256, 0, stream>>>(ei, E, N, offs, fillc, csr);
    aggregate<<<N, 256, 0, stream>>>(h, a_src, a_dst, offs, csr, bias, out, N);
}

// Round 3
// 207.588 us; speedup vs baseline: 1.3733x; 1.3733x over previous
//
#include <hip/hip_runtime.h>

#define D_IN   128
#define NHEAD  4
#define D_OUT  128
#define HDIM   512   // NHEAD * D_OUT
#define NEG    0.2f

// ---------------------------------------------------------------------------
// Kernel 1: h = x @ W  (M x 128)*(128 x 512) fp32 vector GEMM, 64x64 tile,
// fused epilogue: a_src[n,h] / a_dst[n,h] partial dots via shfl + atomicAdd.
// ---------------------------------------------------------------------------
__global__ __launch_bounds__(256) void gemm_h(const float* __restrict__ x,
                                              const float* __restrict__ W,
                                              const float* __restrict__ att_src,
                                              const float* __restrict__ att_dst,
                                              float* __restrict__ h,
                                              float* __restrict__ a_src,
                                              float* __restrict__ a_dst, int M) {
    __shared__ float AsT[64][68];   // [k][row]
    __shared__ float Bs[64][68];    // [k][col]
    const int tid  = threadIdx.x;
    const int row0 = blockIdx.x * 64;
    const int col0 = blockIdx.y * 64;
    const int tx = tid & 15, ty = tid >> 4;

    float c[4][4] = {};

    for (int kb = 0; kb < 128; kb += 64) {
#pragma unroll
        for (int it = 0; it < 4; ++it) {
            int flat = tid + it * 256;
            int r  = flat >> 4;
            int kf = flat & 15;
            int grow = row0 + r; if (grow >= M) grow = M - 1;
            float4 v = *(const float4*)(x + (size_t)grow * D_IN + kb + kf * 4);
            AsT[kf * 4 + 0][r] = v.x;
            AsT[kf * 4 + 1][r] = v.y;
            AsT[kf * 4 + 2][r] = v.z;
            AsT[kf * 4 + 3][r] = v.w;
        }
#pragma unroll
        for (int it = 0; it < 4; ++it) {
            int flat = tid + it * 256;
            int r  = flat >> 4;
            int cf = flat & 15;
            float4 v = *(const float4*)(W + (size_t)(kb + r) * HDIM + col0 + cf * 4);
            *(float4*)(&Bs[r][cf * 4]) = v;
        }
        __syncthreads();

#pragma unroll 4
        for (int kk = 0; kk < 64; ++kk) {
            float4 a = *(const float4*)(&AsT[kk][ty * 4]);
            float4 b = *(const float4*)(&Bs[kk][tx * 4]);
            const float* af = reinterpret_cast<const float*>(&a);
            const float* bf = reinterpret_cast<const float*>(&b);
#pragma unroll
            for (int i = 0; i < 4; ++i)
#pragma unroll
                for (int j = 0; j < 4; ++j)
                    c[i][j] += af[i] * bf[j];
        }
        __syncthreads();
    }

    // store h tile
#pragma unroll
    for (int i = 0; i < 4; ++i) {
        int grow = row0 + ty * 4 + i;
        if (grow < M) {
            float4 v = make_float4(c[i][0], c[i][1], c[i][2], c[i][3]);
            *(float4*)(h + (size_t)grow * HDIM + col0 + tx * 4) = v;
        }
    }

    // fused attention-half epilogue: this block covers cols [col0,col0+64)
    // which lie inside head (col0>>7). Partial dot over our 4 cols, reduce
    // across the 16 tx lanes (contiguous in wave), atomicAdd per (row,head).
    const int head = col0 >> 7;
    float as4[4], ad4[4];
#pragma unroll
    for (int j = 0; j < 4; ++j) {
        as4[j] = att_src[col0 + tx * 4 + j];
        ad4[j] = att_dst[col0 + tx * 4 + j];
    }
#pragma unroll
    for (int i = 0; i < 4; ++i) {
        float ps = c[i][0] * as4[0] + c[i][1] * as4[1] + c[i][2] * as4[2] + c[i][3] * as4[3];
        float pd = c[i][0] * ad4[0] + c[i][1] * ad4[1] + c[i][2] * ad4[2] + c[i][3] * ad4[3];
#pragma unroll
        for (int off = 8; off; off >>= 1) {
            ps += __shfl_xor(ps, off, 16);
            pd += __shfl_xor(pd, off, 16);
        }
        if (tx == 0) {
            int grow = row0 + ty * 4 + i;
            if (grow < M) {
                atomicAdd(&a_src[grow * NHEAD + head], ps);
                atomicAdd(&a_dst[grow * NHEAD + head], pd);
            }
        }
    }
}

// ---------------------------------------------------------------------------
// CSR build (self-loops appended). edge_index arrives as int32.
// ---------------------------------------------------------------------------
__global__ void count_deg(const int* __restrict__ ei, int E, int Nn,
                          int* __restrict__ deg) {
    int i = blockIdx.x * blockDim.x + threadIdx.x;
    if (i >= E + Nn) return;
    int dst = (i < E) ? ei[E + i] : (i - E);
    atomicAdd(&deg[dst], 1);
}

// chunked scan: 1024 threads x 32 elems = up to 32768 (N = 20000 fits)
__global__ __launch_bounds__(1024) void scan_offsets(const int* __restrict__ deg,
                                                     int* __restrict__ offs, int n) {
    const int C = 32;
    int t = threadIdx.x;
    int base = t * C;
    int local[C];
    int sum = 0;
#pragma unroll
    for (int j = 0; j < C; ++j) {
        int i = base + j;
        int v = (i < n) ? deg[i] : 0;
        sum += v;
        local[j] = sum;               // inclusive within chunk
    }
    int lane = t & 63, wave = t >> 6;
    int v = sum;
#pragma unroll
    for (int off = 1; off < 64; off <<= 1) {
        int u = __shfl_up(v, off);
        if (lane >= off) v += u;      // inclusive over lanes
    }
    __shared__ int wsum[16];
    __shared__ int wpre[16];
    if (lane == 63) wsum[wave] = v;
    __syncthreads();
    if (t < 16) {
        int wv = wsum[t];
#pragma unroll
        for (int off = 1; off < 16; off <<= 1) {
            int u = __shfl_up(wv, off, 16);
            if (t >= off) wv += u;
        }
        wpre[t] = wv;                 // inclusive wave prefix
    }
    __syncthreads();
    int excl_in_wave = v - sum;
    int wbase = (wave > 0) ? wpre[wave - 1] : 0;
    int tbase = wbase + excl_in_wave; // exclusive prefix of this chunk
#pragma unroll
    for (int j = 0; j < C; ++j) {
        int i = base + j;
        if (i < n) offs[i + 1] = tbase + local[j];
    }
    if (t == 0) offs[0] = 0;
}

// fill CSR and per-edge softmax numerators w[e][h] = exp(leaky(logit))
__global__ void fill_csr(const int* __restrict__ ei, int E, int Nn,
                         const int* __restrict__ offs, int* __restrict__ fill,
                         const float* __restrict__ a_src,
                         const float* __restrict__ a_dst,
                         int* __restrict__ csr, float* __restrict__ wts) {
    int i = blockIdx.x * blockDim.x + threadIdx.x;
    if (i >= E + Nn) return;
    int src, dst;
    if (i < E) { src = ei[i]; dst = ei[E + i]; }
    else       { src = dst = i - E; }
    int pos = offs[dst] + atomicAdd(&fill[dst], 1);
    csr[pos] = src;
    const float4 as = *(const float4*)(a_src + src * NHEAD);
    const float4 ad = *(const float4*)(a_dst + dst * NHEAD);
    float4 w;
    float l;
    l = as.x + ad.x; l = (l >= 0.f) ? l : NEG * l; w.x = __expf(l);
    l = as.y + ad.y; l = (l >= 0.f) ? l : NEG * l; w.y = __expf(l);
    l = as.z + ad.z; l = (l >= 0.f) ? l : NEG * l; w.z = __expf(l);
    l = as.w + ad.w; l = (l >= 0.f) ? l : NEG * l; w.w = __expf(l);
    *(float4*)(wts + (size_t)pos * NHEAD) = w;
}

// ---------------------------------------------------------------------------
// aggregate: single pass. thread t owns flat dims {2t, 2t+1} (head = t>>6).
// per edge: broadcast csr + broadcast w + one coalesced float2 gather + 2 FMA.
// ---------------------------------------------------------------------------
__global__ __launch_bounds__(256) void aggregate(const float* __restrict__ h,
                                                 const int* __restrict__ offs,
                                                 const int* __restrict__ csr,
                                                 const float* __restrict__ wts,
                                                 const float* __restrict__ bias,
                                                 float* __restrict__ out, int Nn) {
    int n = blockIdx.x;
    int tid = threadIdx.x;
    int beg = offs[n], end = offs[n + 1];
    const int hsel = tid >> 6;
    const float2* __restrict__ h2 = (const float2*)h;

    float2 acc0 = {0.f, 0.f}, acc1 = {0.f, 0.f};
    float den0 = 0.f, den1 = 0.f;
    int e = beg;
    for (; e + 1 < end; e += 2) {
        int s0 = csr[e], s1 = csr[e + 1];
        float w0 = wts[(size_t)e * NHEAD + hsel];
        float w1 = wts[(size_t)(e + 1) * NHEAD + hsel];
        float2 v0 = h2[s0 * 256 + tid];
        float2 v1 = h2[s1 * 256 + tid];
        acc0.x += w0 * v0.x; acc0.y += w0 * v0.y; den0 += w0;
        acc1.x += w1 * v1.x; acc1.y += w1 * v1.y; den1 += w1;
    }
    if (e < end) {
        int s0 = csr[e];
        float w0 = wts[(size_t)e * NHEAD + hsel];
        float2 v0 = h2[s0 * 256 + tid];
        acc0.x += w0 * v0.x; acc0.y += w0 * v0.y; den0 += w0;
    }
    float den = den0 + den1;
    float inv = 1.0f / den;
    float r0 = (acc0.x + acc1.x) * inv;
    float r1 = (acc0.y + acc1.y) * inv;

    __shared__ float red[512];
    red[2 * tid]     = r0;
    red[2 * tid + 1] = r1;
    __syncthreads();
    if (tid < 128) {
        float vsum = red[tid] + red[tid + 128] + red[tid + 256] + red[tid + 384];
        vsum = vsum * 0.25f + bias[tid];
        out[(size_t)n * D_OUT + tid] = fmaxf(vsum, 0.f);
    }
}

// ---------------------------------------------------------------------------
extern "C" void kernel_launch(void* const* d_in, const int* in_sizes, int n_in,
                              void* d_out, int out_size, void* d_ws, size_t ws_size,
                              hipStream_t stream) {
    const float* x       = (const float*)d_in[0];
    const float* W       = (const float*)d_in[1];
    const float* att_src = (const float*)d_in[2];
    const float* att_dst = (const float*)d_in[3];
    const float* bias    = (const float*)d_in[4];
    const int*   ei      = (const int*)d_in[5];
    float*       out     = (float*)d_out;

    const int N    = in_sizes[0] / D_IN;
    const int E    = in_sizes[5] / 2;
    const int Etot = E + N;

    char* ws = (char*)d_ws;
    size_t off = 0;
    auto alloc = [&](size_t bytes) -> char* {
        char* p = ws + off;
        off += (bytes + 255) & ~(size_t)255;
        return p;
    };
    float* h     = (float*)alloc((size_t)N * HDIM * sizeof(float));
    float* a_src = (float*)alloc((size_t)N * NHEAD * sizeof(float));
    float* a_dst = (float*)alloc((size_t)N * NHEAD * sizeof(float));
    int*   deg   = (int*)alloc((size_t)N * sizeof(int));
    int*   offs  = (int*)alloc((size_t)(N + 1) * sizeof(int));
    int*   fillc = (int*)alloc((size_t)N * sizeof(int));
    int*   csr   = (int*)alloc((size_t)Etot * sizeof(int));
    float* wts   = (float*)alloc((size_t)Etot * NHEAD * sizeof(float));

    hipMemsetAsync(deg,   0, (size_t)N * sizeof(int), stream);
    hipMemsetAsync(fillc, 0, (size_t)N * sizeof(int), stream);
    hipMemsetAsync(a_src, 0, (size_t)N * NHEAD * sizeof(float), stream);
    hipMemsetAsync(a_dst, 0, (size_t)N * NHEAD * sizeof(float), stream);

    dim3 ggrid((N + 63) / 64, HDIM / 64);
    gemm_h<<<ggrid, 256, 0, stream>>>(x, W, att_src, att_dst, h, a_src, a_dst, N);
    count_deg<<<(Etot + 255) / 256, 256, 0, stream>>>(ei, E, N, deg);
    scan_offsets<<<1, 1024, 0, stream>>>(deg, offs, N);
    fill_csr<<<(Etot + 255) / 256, 256, 0, stream>>>(ei, E, N, offs, fillc,
                                                     a_src, a_dst, csr, wts);
    aggregate<<<N, 256, 0, stream>>>(h, offs, csr, wts, bias, out, N);
}

// Round 4
// 166.179 us; speedup vs baseline: 1.7155x; 1.2492x over previous
//
#include <hip/hip_runtime.h>

#define D_IN   128
#define NHEAD  4
#define D_OUT  128
#define HDIM   512   // NHEAD * D_OUT
#define NEG    0.2f

// pack two fp32 -> bf16x2 (round-to-nearest-even)
__device__ __forceinline__ unsigned pack_bf16(float a, float b) {
    unsigned ua = __float_as_uint(a);
    unsigned ub = __float_as_uint(b);
    ua = (ua + 0x7fffu + ((ua >> 16) & 1u)) >> 16;
    ub = (ub + 0x7fffu + ((ub >> 16) & 1u)) >> 16;
    return ua | (ub << 16);
}

// ---------------------------------------------------------------------------
// Kernel 1: h = x @ W  (M x 128)*(128 x 512) fp32 vector GEMM, 64x64 tile.
// Epilogue: store h as bf16x2 + fused a_src/a_dst partial dots (fp32, atomic).
// ---------------------------------------------------------------------------
__global__ __launch_bounds__(256) void gemm_h(const float* __restrict__ x,
                                              const float* __restrict__ W,
                                              const float* __restrict__ att_src,
                                              const float* __restrict__ att_dst,
                                              unsigned* __restrict__ hb,
                                              float* __restrict__ a_src,
                                              float* __restrict__ a_dst, int M) {
    __shared__ float AsT[64][68];   // [k][row]
    __shared__ float Bs[64][68];    // [k][col]
    const int tid  = threadIdx.x;
    const int row0 = blockIdx.x * 64;
    const int col0 = blockIdx.y * 64;
    const int tx = tid & 15, ty = tid >> 4;

    float c[4][4] = {};

    for (int kb = 0; kb < 128; kb += 64) {
#pragma unroll
        for (int it = 0; it < 4; ++it) {
            int flat = tid + it * 256;
            int r  = flat >> 4;
            int kf = flat & 15;
            int grow = row0 + r; if (grow >= M) grow = M - 1;
            float4 v = *(const float4*)(x + (size_t)grow * D_IN + kb + kf * 4);
            AsT[kf * 4 + 0][r] = v.x;
            AsT[kf * 4 + 1][r] = v.y;
            AsT[kf * 4 + 2][r] = v.z;
            AsT[kf * 4 + 3][r] = v.w;
        }
#pragma unroll
        for (int it = 0; it < 4; ++it) {
            int flat = tid + it * 256;
            int r  = flat >> 4;
            int cf = flat & 15;
            float4 v = *(const float4*)(W + (size_t)(kb + r) * HDIM + col0 + cf * 4);
            *(float4*)(&Bs[r][cf * 4]) = v;
        }
        __syncthreads();

#pragma unroll 4
        for (int kk = 0; kk < 64; ++kk) {
            float4 a = *(const float4*)(&AsT[kk][ty * 4]);
            float4 b = *(const float4*)(&Bs[kk][tx * 4]);
            const float* af = reinterpret_cast<const float*>(&a);
            const float* bf = reinterpret_cast<const float*>(&b);
#pragma unroll
            for (int i = 0; i < 4; ++i)
#pragma unroll
                for (int j = 0; j < 4; ++j)
                    c[i][j] += af[i] * bf[j];
        }
        __syncthreads();
    }

    // store h tile as bf16x2 (uint2 per thread-row)
#pragma unroll
    for (int i = 0; i < 4; ++i) {
        int grow = row0 + ty * 4 + i;
        if (grow < M) {
            uint2 u;
            u.x = pack_bf16(c[i][0], c[i][1]);
            u.y = pack_bf16(c[i][2], c[i][3]);
            *(uint2*)(hb + (size_t)grow * 256 + (col0 >> 1) + tx * 2) = u;
        }
    }

    // fused attention-half epilogue (fp32): cols [col0,col0+64) lie in head col0>>7
    const int head = col0 >> 7;
    float as4[4], ad4[4];
#pragma unroll
    for (int j = 0; j < 4; ++j) {
        as4[j] = att_src[col0 + tx * 4 + j];
        ad4[j] = att_dst[col0 + tx * 4 + j];
    }
#pragma unroll
    for (int i = 0; i < 4; ++i) {
        float ps = c[i][0] * as4[0] + c[i][1] * as4[1] + c[i][2] * as4[2] + c[i][3] * as4[3];
        float pd = c[i][0] * ad4[0] + c[i][1] * ad4[1] + c[i][2] * ad4[2] + c[i][3] * ad4[3];
#pragma unroll
        for (int off = 8; off; off >>= 1) {
            ps += __shfl_xor(ps, off, 16);
            pd += __shfl_xor(pd, off, 16);
        }
        if (tx == 0) {
            int grow = row0 + ty * 4 + i;
            if (grow < M) {
                atomicAdd(&a_src[grow * NHEAD + head], ps);
                atomicAdd(&a_dst[grow * NHEAD + head], pd);
            }
        }
    }
}

// ---------------------------------------------------------------------------
// CSR build (self-loops appended). edge_index arrives as int32.
// ---------------------------------------------------------------------------
__global__ void count_deg(const int* __restrict__ ei, int E, int Nn,
                          int* __restrict__ deg) {
    int i = blockIdx.x * blockDim.x + threadIdx.x;
    if (i >= E + Nn) return;
    int dst = (i < E) ? ei[E + i] : (i - E);
    atomicAdd(&deg[dst], 1);
}

// chunked scan: 1024 threads x 32 elems = up to 32768 (N = 20000 fits)
__global__ __launch_bounds__(1024) void scan_offsets(const int* __restrict__ deg,
                                                     int* __restrict__ offs, int n) {
    const int C = 32;
    int t = threadIdx.x;
    int base = t * C;
    int local[C];
    int sum = 0;
#pragma unroll
    for (int j = 0; j < C; ++j) {
        int i = base + j;
        int v = (i < n) ? deg[i] : 0;
        sum += v;
        local[j] = sum;               // inclusive within chunk
    }
    int lane = t & 63, wave = t >> 6;
    int v = sum;
#pragma unroll
    for (int off = 1; off < 64; off <<= 1) {
        int u = __shfl_up(v, off);
        if (lane >= off) v += u;      // inclusive over lanes
    }
    __shared__ int wsum[16];
    __shared__ int wpre[16];
    if (lane == 63) wsum[wave] = v;
    __syncthreads();
    if (t < 16) {
        int wv = wsum[t];
#pragma unroll
        for (int off = 1; off < 16; off <<= 1) {
            int u = __shfl_up(wv, off, 16);
            if (t >= off) wv += u;
        }
        wpre[t] = wv;                 // inclusive wave prefix
    }
    __syncthreads();
    int excl_in_wave = v - sum;
    int wbase = (wave > 0) ? wpre[wave - 1] : 0;
    int tbase = wbase + excl_in_wave; // exclusive prefix of this chunk
#pragma unroll
    for (int j = 0; j < C; ++j) {
        int i = base + j;
        if (i < n) offs[i + 1] = tbase + local[j];
    }
    if (t == 0) offs[0] = 0;
}

// fill CSR and per-edge softmax numerators w[e][h] = exp(leaky(logit))
__global__ void fill_csr(const int* __restrict__ ei, int E, int Nn,
                         const int* __restrict__ offs, int* __restrict__ fill,
                         const float* __restrict__ a_src,
                         const float* __restrict__ a_dst,
                         int* __restrict__ csr, float* __restrict__ wts) {
    int i = blockIdx.x * blockDim.x + threadIdx.x;
    if (i >= E + Nn) return;
    int src, dst;
    if (i < E) { src = ei[i]; dst = ei[E + i]; }
    else       { src = dst = i - E; }
    int pos = offs[dst] + atomicAdd(&fill[dst], 1);
    csr[pos] = src;
    const float4 as = *(const float4*)(a_src + src * NHEAD);
    const float4 ad = *(const float4*)(a_dst + dst * NHEAD);
    float4 w;
    float l;
    l = as.x + ad.x; l = (l >= 0.f) ? l : NEG * l; w.x = __expf(l);
    l = as.y + ad.y; l = (l >= 0.f) ? l : NEG * l; w.y = __expf(l);
    l = as.z + ad.z; l = (l >= 0.f) ? l : NEG * l; w.z = __expf(l);
    l = as.w + ad.w; l = (l >= 0.f) ? l : NEG * l; w.w = __expf(l);
    *(float4*)(wts + (size_t)pos * NHEAD) = w;
}

// ---------------------------------------------------------------------------
// aggregate: single pass over bf16 h. thread t owns flat dims {2t, 2t+1}
// (head = t>>6). per edge: one coalesced u32 gather (2 bf16) + unpack + 2 FMA.
// ---------------------------------------------------------------------------
__global__ __launch_bounds__(256) void aggregate(const unsigned* __restrict__ hb,
                                                 const int* __restrict__ offs,
                                                 const int* __restrict__ csr,
                                                 const float* __restrict__ wts,
                                                 const float* __restrict__ bias,
                                                 float* __restrict__ out, int Nn) {
    int n = blockIdx.x;
    int tid = threadIdx.x;
    int beg = offs[n], end = offs[n + 1];
    const int hsel = tid >> 6;

    float a0 = 0.f, b0 = 0.f, a1 = 0.f, b1 = 0.f;
    float den0 = 0.f, den1 = 0.f;
    int e = beg;
    for (; e + 1 < end; e += 2) {
        int s0 = csr[e], s1 = csr[e + 1];
        float w0 = wts[(size_t)e * NHEAD + hsel];
        float w1 = wts[(size_t)(e + 1) * NHEAD + hsel];
        unsigned v0 = hb[(size_t)s0 * 256 + tid];
        unsigned v1 = hb[(size_t)s1 * 256 + tid];
        float f00 = __uint_as_float(v0 << 16);
        float f01 = __uint_as_float(v0 & 0xffff0000u);
        float f10 = __uint_as_float(v1 << 16);
        float f11 = __uint_as_float(v1 & 0xffff0000u);
        a0 += w0 * f00; b0 += w0 * f01; den0 += w0;
        a1 += w1 * f10; b1 += w1 * f11; den1 += w1;
    }
    if (e < end) {
        int s0 = csr[e];
        float w0 = wts[(size_t)e * NHEAD + hsel];
        unsigned v0 = hb[(size_t)s0 * 256 + tid];
        a0 += w0 * __uint_as_float(v0 << 16);
        b0 += w0 * __uint_as_float(v0 & 0xffff0000u);
        den0 += w0;
    }
    float inv = 1.0f / (den0 + den1);
    float r0 = (a0 + a1) * inv;
    float r1 = (b0 + b1) * inv;

    __shared__ float red[512];
    red[2 * tid]     = r0;
    red[2 * tid + 1] = r1;
    __syncthreads();
    if (tid < 128) {
        float vsum = red[tid] + red[tid + 128] + red[tid + 256] + red[tid + 384];
        vsum = vsum * 0.25f + bias[tid];
        out[(size_t)n * D_OUT + tid] = fmaxf(vsum, 0.f);
    }
}

// ---------------------------------------------------------------------------
extern "C" void kernel_launch(void* const* d_in, const int* in_sizes, int n_in,
                              void* d_out, int out_size, void* d_ws, size_t ws_size,
                              hipStream_t stream) {
    const float* x       = (const float*)d_in[0];
    const float* W       = (const float*)d_in[1];
    const float* att_src = (const float*)d_in[2];
    const float* att_dst = (const float*)d_in[3];
    const float* bias    = (const float*)d_in[4];
    const int*   ei      = (const int*)d_in[5];
    float*       out     = (float*)d_out;

    const int N    = in_sizes[0] / D_IN;
    const int E    = in_sizes[5] / 2;
    const int Etot = E + N;

    char* ws = (char*)d_ws;
    size_t off = 0;
    auto alloc = [&](size_t bytes) -> char* {
        char* p = ws + off;
        off += (bytes + 255) & ~(size_t)255;
        return p;
    };
    unsigned* hb    = (unsigned*)alloc((size_t)N * 256 * sizeof(unsigned)); // bf16x2
    // contiguous zero-init region: a_src, a_dst, deg, fillc
    float* a_src = (float*)alloc((size_t)N * NHEAD * sizeof(float));
    float* a_dst = (float*)alloc((size_t)N * NHEAD * sizeof(float));
    int*   deg   = (int*)alloc((size_t)N * sizeof(int));
    int*   fillc = (int*)alloc((size_t)N * sizeof(int));
    size_t zspan = (size_t)((char*)(fillc + N) - (char*)a_src);
    int*   offs  = (int*)alloc((size_t)(N + 1) * sizeof(int));
    int*   csr   = (int*)alloc((size_t)Etot * sizeof(int));
    float* wts   = (float*)alloc((size_t)Etot * NHEAD * sizeof(float));

    hipMemsetAsync(a_src, 0, zspan, stream);

    dim3 ggrid((N + 63) / 64, HDIM / 64);
    gemm_h<<<ggrid, 256, 0, stream>>>(x, W, att_src, att_dst, hb, a_src, a_dst, N);
    count_deg<<<(Etot + 255) / 256, 256, 0, stream>>>(ei, E, N, deg);
    scan_offsets<<<1, 1024, 0, stream>>>(deg, offs, N);
    fill_csr<<<(Etot + 255) / 256, 256, 0, stream>>>(ei, E, N, offs, fillc,
                                                     a_src, a_dst, csr, wts);
    aggregate<<<N, 256, 0, stream>>>(hb, offs, csr, wts, bias, out, N);
}

// Round 5
// 135.727 us; speedup vs baseline: 2.1004x; 1.2244x over previous
//
#include <hip/hip_runtime.h>

#define NHEAD  4
#define D_OUT  128
#define HDIM   512   // NHEAD * D_OUT
#define NEG    0.2f

typedef __attribute__((ext_vector_type(8))) short short8;
typedef __attribute__((ext_vector_type(4))) float f32x4;

// pack two fp32 -> bf16x2 (round-to-nearest-even)
__device__ __forceinline__ unsigned pack_bf16(float a, float b) {
    unsigned ua = __float_as_uint(a);
    unsigned ub = __float_as_uint(b);
    ua = (ua + 0x7fffu + ((ua >> 16) & 1u)) >> 16;
    ub = (ub + 0x7fffu + ((ub >> 16) & 1u)) >> 16;
    return ua | (ub << 16);
}
__device__ __forceinline__ float bf_lo(unsigned u) { return __uint_as_float(u << 16); }
__device__ __forceinline__ float bf_hi(unsigned u) { return __uint_as_float(u & 0xffff0000u); }

// ---------------------------------------------------------------------------
// convert W (128 x 512 fp32) -> Wt (512 x 128 bf16), transposed for MFMA B-op
// ---------------------------------------------------------------------------
__global__ __launch_bounds__(256) void convert_w(const float* __restrict__ W,
                                                 ushort* __restrict__ Wt) {
    int t = blockIdx.x * 256 + threadIdx.x;    // 4096 threads: 128 c4 x 32 kq
    int c = (t >> 5) * 4;
    int k = (t & 31) * 4;
    float4 r0 = *(const float4*)(W + (size_t)(k + 0) * HDIM + c);
    float4 r1 = *(const float4*)(W + (size_t)(k + 1) * HDIM + c);
    float4 r2 = *(const float4*)(W + (size_t)(k + 2) * HDIM + c);
    float4 r3 = *(const float4*)(W + (size_t)(k + 3) * HDIM + c);
    const float* f0 = (const float*)&r0;
    const float* f1 = (const float*)&r1;
    const float* f2 = (const float*)&r2;
    const float* f3 = (const float*)&r3;
#pragma unroll
    for (int j = 0; j < 4; ++j) {
        uint2 u;
        u.x = pack_bf16(f0[j], f1[j]);
        u.y = pack_bf16(f2[j], f3[j]);
        *(uint2*)(Wt + (size_t)(c + j) * 128 + k) = u;
    }
}

// ---------------------------------------------------------------------------
// gemm_h: h[M][512] = x[M][128] @ W, bf16 MFMA (16x16x32), one head per
// blockIdx.y. Block tile 128 rows x 128 cols; wave w owns rows w*32..+31.
// Swapped operands: mfma(B^T-frag, A^T-frag) -> D^T: lane holds 4 consecutive
// cols per acc reg -> direct bf16x2 pack; full head per wave -> a_src/a_dst
// dots finished in-wave, no atomics. LDS XOR-swizzled (2-way max conflicts).
// ---------------------------------------------------------------------------
__global__ __launch_bounds__(256) void gemm_h(const float* __restrict__ x,
                                              const ushort* __restrict__ Wt,
                                              const float* __restrict__ att_src,
                                              const float* __restrict__ att_dst,
                                              unsigned* __restrict__ hb,
                                              float* __restrict__ a_src,
                                              float* __restrict__ a_dst, int M) {
    __shared__ ushort As[128 * 128];   // [row][k] bf16, byte ^= ((row&7)<<4)
    __shared__ ushort Bt[128 * 128];   // [col][k] bf16, byte ^= ((col&7)<<4)
    const int tid  = threadIdx.x;
    const int row0 = blockIdx.x * 128;
    const int head = blockIdx.y;
    const int col0 = head * 128;

    // stage A: fp32 -> bf16, 2048 granules of 8 bf16, coalesced reads
#pragma unroll
    for (int it = 0; it < 8; ++it) {
        int flat = tid + it * 256;
        int r = flat >> 4, g = flat & 15;
        int grow = row0 + r; if (grow >= M) grow = M - 1;
        const float* px = x + (size_t)grow * 128 + g * 8;
        float4 a = *(const float4*)px;
        float4 b = *(const float4*)(px + 4);
        uint4 u;
        u.x = pack_bf16(a.x, a.y); u.y = pack_bf16(a.z, a.w);
        u.z = pack_bf16(b.x, b.y); u.w = pack_bf16(b.z, b.w);
        int us = r * 128 + ((g * 8) ^ ((r & 7) << 3));
        *(uint4*)(&As[us]) = u;
    }
    // stage B: Wt already bf16, straight copy with swizzle
#pragma unroll
    for (int it = 0; it < 8; ++it) {
        int flat = tid + it * 256;
        int c = flat >> 4, g = flat & 15;
        uint4 u = *(const uint4*)(Wt + (size_t)(col0 + c) * 128 + g * 8);
        int us = c * 128 + ((g * 8) ^ ((c & 7) << 3));
        *(uint4*)(&Bt[us]) = u;
    }
    __syncthreads();

    const int w  = tid >> 6;      // wave: rows w*32 .. +31
    const int l  = tid & 63;
    const int lr = l & 15;        // row/col-in-frag
    const int lk = l >> 4;        // k-subgroup

    f32x4 acc[8][2];              // [cr][rr]
#pragma unroll
    for (int cr = 0; cr < 8; ++cr)
#pragma unroll
        for (int rr = 0; rr < 2; ++rr) acc[cr][rr] = (f32x4){0.f, 0.f, 0.f, 0.f};

#pragma unroll
    for (int kg = 0; kg < 4; ++kg) {
        short8 af[2];
#pragma unroll
        for (int rr = 0; rr < 2; ++rr) {
            int row = w * 32 + rr * 16 + lr;
            int us = row * 128 + ((kg * 32 + lk * 8) ^ ((row & 7) << 3));
            af[rr] = *(const short8*)(&As[us]);
        }
#pragma unroll
        for (int cr = 0; cr < 8; ++cr) {
            int col = cr * 16 + lr;
            int us = col * 128 + ((kg * 32 + lk * 8) ^ ((col & 7) << 3));
            short8 bf = *(const short8*)(&Bt[us]);
#pragma unroll
            for (int rr = 0; rr < 2; ++rr)
                acc[cr][rr] = __builtin_amdgcn_mfma_f32_16x16x32_bf16(
                    bf, af[rr], acc[cr][rr], 0, 0, 0);
        }
    }

    // epilogue: lane holds rows (w*32+rr*16+lr), cols (cr*16+lk*4+reg)
    float4 avs[8], avd[8];
#pragma unroll
    for (int cr = 0; cr < 8; ++cr) {
        avs[cr] = *(const float4*)(att_src + col0 + cr * 16 + lk * 4);
        avd[cr] = *(const float4*)(att_dst + col0 + cr * 16 + lk * 4);
    }
#pragma unroll
    for (int rr = 0; rr < 2; ++rr) {
        uint2 u8[8];
        float ps = 0.f, pd = 0.f;
#pragma unroll
        for (int cr = 0; cr < 8; ++cr) {
            f32x4 c4 = acc[cr][rr];
            u8[cr].x = pack_bf16(c4[0], c4[1]);
            u8[cr].y = pack_bf16(c4[2], c4[3]);
            ps += c4[0] * avs[cr].x + c4[1] * avs[cr].y + c4[2] * avs[cr].z + c4[3] * avs[cr].w;
            pd += c4[0] * avd[cr].x + c4[1] * avd[cr].y + c4[2] * avd[cr].z + c4[3] * avd[cr].w;
        }
        ps += __shfl_xor(ps, 16); ps += __shfl_xor(ps, 32);
        pd += __shfl_xor(pd, 16); pd += __shfl_xor(pd, 32);
        int row = row0 + w * 32 + rr * 16 + lr;
        if (row < M) {
#pragma unroll
            for (int cr = 0; cr < 8; ++cr)
                *(uint2*)(hb + (size_t)row * 256 + head * 64 + cr * 8 + lk * 2) = u8[cr];
            if (lk == 0) {
                a_src[row * NHEAD + head] = ps;
                a_dst[row * NHEAD + head] = pd;
            }
        }
    }
}

// ---------------------------------------------------------------------------
// CSR build (self-loops appended). edge_index arrives as int32.
// ---------------------------------------------------------------------------
__global__ void count_deg(const int* __restrict__ ei, int E, int Nn,
                          int* __restrict__ deg) {
    int i = blockIdx.x * blockDim.x + threadIdx.x;
    if (i >= E + Nn) return;
    int dst = (i < E) ? ei[E + i] : (i - E);
    atomicAdd(&deg[dst], 1);
}

// chunked scan: 1024 threads x 32 elems = up to 32768 (N = 20000 fits)
__global__ __launch_bounds__(1024) void scan_offsets(const int* __restrict__ deg,
                                                     int* __restrict__ offs, int n) {
    const int C = 32;
    int t = threadIdx.x;
    int base = t * C;
    int local[C];
    int sum = 0;
#pragma unroll
    for (int j = 0; j < C; ++j) {
        int i = base + j;
        int v = (i < n) ? deg[i] : 0;
        sum += v;
        local[j] = sum;
    }
    int lane = t & 63, wave = t >> 6;
    int v = sum;
#pragma unroll
    for (int off = 1; off < 64; off <<= 1) {
        int u = __shfl_up(v, off);
        if (lane >= off) v += u;
    }
    __shared__ int wsum[16];
    __shared__ int wpre[16];
    if (lane == 63) wsum[wave] = v;
    __syncthreads();
    if (t < 16) {
        int wv = wsum[t];
#pragma unroll
        for (int off = 1; off < 16; off <<= 1) {
            int u = __shfl_up(wv, off, 16);
            if (t >= off) wv += u;
        }
        wpre[t] = wv;
    }
    __syncthreads();
    int excl_in_wave = v - sum;
    int wbase = (wave > 0) ? wpre[wave - 1] : 0;
    int tbase = wbase + excl_in_wave;
#pragma unroll
    for (int j = 0; j < C; ++j) {
        int i = base + j;
        if (i < n) offs[i + 1] = tbase + local[j];
    }
    if (t == 0) offs[0] = 0;
}

// fill CSR and per-edge softmax numerators w[e][h] = exp(leaky(logit))
__global__ void fill_csr(const int* __restrict__ ei, int E, int Nn,
                         const int* __restrict__ offs, int* __restrict__ fill,
                         const float* __restrict__ a_src,
                         const float* __restrict__ a_dst,
                         int* __restrict__ csr, float* __restrict__ wts) {
    int i = blockIdx.x * blockDim.x + threadIdx.x;
    if (i >= E + Nn) return;
    int src, dst;
    if (i < E) { src = ei[i]; dst = ei[E + i]; }
    else       { src = dst = i - E; }
    int pos = offs[dst] + atomicAdd(&fill[dst], 1);
    csr[pos] = src;
    const float4 as = *(const float4*)(a_src + src * NHEAD);
    const float4 ad = *(const float4*)(a_dst + dst * NHEAD);
    float4 w;
    float l;
    l = as.x + ad.x; l = (l >= 0.f) ? l : NEG * l; w.x = __expf(l);
    l = as.y + ad.y; l = (l >= 0.f) ? l : NEG * l; w.y = __expf(l);
    l = as.z + ad.z; l = (l >= 0.f) ? l : NEG * l; w.z = __expf(l);
    l = as.w + ad.w; l = (l >= 0.f) ? l : NEG * l; w.w = __expf(l);
    *(float4*)(wts + (size_t)pos * NHEAD) = w;
}

// ---------------------------------------------------------------------------
// aggregate: one WAVE per node (4 nodes/block) -> 4 independent edge streams
// per block (4x MLP), 16B/lane uint4 gathers, no __syncthreads.
// lane l: head l>>4, bf16 dims 8l..8l+7; head-mean via 2x shfl_xor.
// ---------------------------------------------------------------------------
__global__ __launch_bounds__(256) void aggregate(const uint4* __restrict__ hb4,
                                                 const int* __restrict__ offs,
                                                 const int* __restrict__ csr,
                                                 const float* __restrict__ wts,
                                                 const float* __restrict__ bias,
                                                 float* __restrict__ out, int Nn) {
    int n = blockIdx.x * 4 + (threadIdx.x >> 6);
    if (n >= Nn) return;
    int l  = threadIdx.x & 63;
    int hd = l >> 4;
    int beg = offs[n], end = offs[n + 1];

    float a0 = 0.f, a1 = 0.f, a2 = 0.f, a3 = 0.f;
    float a4 = 0.f, a5 = 0.f, a6 = 0.f, a7 = 0.f;
    float den = 0.f;
    if (beg < end) {
        int s = csr[beg];
        float wc = wts[(size_t)beg * NHEAD + hd];
        for (int e = beg;;) {
            uint4 v = hb4[(size_t)s * 64 + l];
            float wcur = wc;
            ++e;
            bool more = e < end;
            if (more) {                         // prefetch next edge's s,w
                s  = csr[e];
                wc = wts[(size_t)e * NHEAD + hd];
            }
            den += wcur;
            a0 += wcur * bf_lo(v.x); a1 += wcur * bf_hi(v.x);
            a2 += wcur * bf_lo(v.y); a3 += wcur * bf_hi(v.y);
            a4 += wcur * bf_lo(v.z); a5 += wcur * bf_hi(v.z);
            a6 += wcur * bf_lo(v.w); a7 += wcur * bf_hi(v.w);
            if (!more) break;
        }
    }
    float inv = 1.0f / den;
    a0 *= inv; a1 *= inv; a2 *= inv; a3 *= inv;
    a4 *= inv; a5 *= inv; a6 *= inv; a7 *= inv;
    // sum across the 4 heads (lanes l, l^16, l^32, l^48)
    a0 += __shfl_xor(a0, 16); a0 += __shfl_xor(a0, 32);
    a1 += __shfl_xor(a1, 16); a1 += __shfl_xor(a1, 32);
    a2 += __shfl_xor(a2, 16); a2 += __shfl_xor(a2, 32);
    a3 += __shfl_xor(a3, 16); a3 += __shfl_xor(a3, 32);
    a4 += __shfl_xor(a4, 16); a4 += __shfl_xor(a4, 32);
    a5 += __shfl_xor(a5, 16); a5 += __shfl_xor(a5, 32);
    a6 += __shfl_xor(a6, 16); a6 += __shfl_xor(a6, 32);
    a7 += __shfl_xor(a7, 16); a7 += __shfl_xor(a7, 32);
    if (l < 16) {
        float4 b0 = *(const float4*)(bias + l * 8);
        float4 b1 = *(const float4*)(bias + l * 8 + 4);
        float4 o0, o1;
        o0.x = fmaxf(a0 * 0.25f + b0.x, 0.f);
        o0.y = fmaxf(a1 * 0.25f + b0.y, 0.f);
        o0.z = fmaxf(a2 * 0.25f + b0.z, 0.f);
        o0.w = fmaxf(a3 * 0.25f + b0.w, 0.f);
        o1.x = fmaxf(a4 * 0.25f + b1.x, 0.f);
        o1.y = fmaxf(a5 * 0.25f + b1.y, 0.f);
        o1.z = fmaxf(a6 * 0.25f + b1.z, 0.f);
        o1.w = fmaxf(a7 * 0.25f + b1.w, 0.f);
        *(float4*)(out + (size_t)n * D_OUT + l * 8)     = o0;
        *(float4*)(out + (size_t)n * D_OUT + l * 8 + 4) = o1;
    }
}

// ---------------------------------------------------------------------------
extern "C" void kernel_launch(void* const* d_in, const int* in_sizes, int n_in,
                              void* d_out, int out_size, void* d_ws, size_t ws_size,
                              hipStream_t stream) {
    const float* x       = (const float*)d_in[0];
    const float* W       = (const float*)d_in[1];
    const float* att_src = (const float*)d_in[2];
    const float* att_dst = (const float*)d_in[3];
    const float* bias    = (const float*)d_in[4];
    const int*   ei      = (const int*)d_in[5];
    float*       out     = (float*)d_out;

    const int N    = in_sizes[0] / 128;
    const int E    = in_sizes[5] / 2;
    const int Etot = E + N;

    char* ws = (char*)d_ws;
    size_t off = 0;
    auto alloc = [&](size_t bytes) -> char* {
        char* p = ws + off;
        off += (bytes + 255) & ~(size_t)255;
        return p;
    };
    unsigned* hb    = (unsigned*)alloc((size_t)N * 256 * sizeof(unsigned)); // h bf16x2
    ushort*   Wt    = (ushort*)alloc((size_t)HDIM * 128 * sizeof(ushort));  // W^T bf16
    float*    a_src = (float*)alloc((size_t)N * NHEAD * sizeof(float));
    float*    a_dst = (float*)alloc((size_t)N * NHEAD * sizeof(float));
    int*      deg   = (int*)alloc((size_t)N * sizeof(int));
    int*      fillc = (int*)alloc((size_t)N * sizeof(int));
    size_t    zspan = (size_t)((char*)(fillc + N) - (char*)deg);
    int*      offs  = (int*)alloc((size_t)(N + 1) * sizeof(int));
    int*      csr   = (int*)alloc((size_t)Etot * sizeof(int));
    float*    wts   = (float*)alloc((size_t)Etot * NHEAD * sizeof(float));

    hipMemsetAsync(deg, 0, zspan, stream);

    convert_w<<<16, 256, 0, stream>>>(W, Wt);
    dim3 ggrid((N + 127) / 128, NHEAD);
    gemm_h<<<ggrid, 256, 0, stream>>>(x, Wt, att_src, att_dst, hb, a_src, a_dst, N);
    count_deg<<<(Etot + 255) / 256, 256, 0, stream>>>(ei, E, N, deg);
    scan_offsets<<<1, 1024, 0, stream>>>(deg, offs, N);
    fill_csr<<<(Etot + 255) / 256, 256, 0, stream>>>(ei, E, N, offs, fillc,
                                                     a_src, a_dst, csr, wts);
    aggregate<<<(N + 3) / 4, 256, 0, stream>>>((const uint4*)hb, offs, csr, wts,
                                               bias, out, N);
}